// Round 5
// baseline (94.965 us; speedup 1.0000x reference)
//
#include <hip/hip_runtime.h>

// GeneralizedSurfaceLoss on MI355X.
// Chamfer == Chebyshev distance; BAND_WIDTH=3 => 7x7 neighborhood test.
// R1: killed global-atomic serialization (483 -> 95 us).
// R2: nibble-packed separable window (8 px per uint32, shfl horizontal OR,
//     ds_read_b128 vertical OR), strip blocks.
// R4: 512-thread blocks, hoisted probs loads (neutral -> stage1 not the wall).
// R5: single fused kernel. Last-block pattern: per-block partials + counter;
//     the 512th block to finish does the 72-group reduction and final scalar.
//     Removes the finish kernel's launch+drain from the critical path.

#define HH 512
#define WW 512
#define BB 8
#define STRIP 8               // output rows per block; one row per wave
#define SROWS (STRIP + 6)     // staged rows incl. halo = 14
#define NBLK 512              // 64 strips * 8 images
#define PART_OFF 16           // float offset of partials (counter lives at [0])

// ws floats: [0] = completion counter (int, memset to 0 each launch)
//            [PART_OFF + s*NBLK + blockFlat], s = grp*3+cc (0=num,1=den,2=mc),
//            blockFlat = b*64 + strip.

__global__ __launch_bounds__(512) void gsl_fused(
    const float* __restrict__ probs,   // [B,4,H,W]
    const int*   __restrict__ target,  // [B,H,W]
    float* __restrict__ ws,
    float* __restrict__ out)
{
    __shared__ uint4 hrow[SROWS * 64];   // {h1,h2,h3,center} per (row,lane)
    __shared__ float redf[8][3];
    __shared__ int   redi[8][3];
    __shared__ int   isLast;
    __shared__ float ws2[72];

    const int tid   = threadIdx.x;
    const int lane  = tid & 63;
    const int wave  = tid >> 6;          // 0..7 = output row within strip
    const int strip = blockIdx.x;        // 0..63
    const int b     = blockIdx.y;        // 0..7
    const int y0    = strip * STRIP;
    const int gy    = y0 + wave;
    const int* __restrict__ tgt_b = target + b * (HH * WW);

    // ---- probs for this wave's row: 6 independent float4 loads up front.
    const float4* pr1 = (const float4*)(probs + (size_t)(((b * 4) + 1) * HH + gy) * WW);
    const float4* pr2 = (const float4*)(probs + (size_t)(((b * 4) + 2) * HH + gy) * WW);
    const float4* pr3 = (const float4*)(probs + (size_t)(((b * 4) + 3) * HH + gy) * WW);
    const float4 f1a = pr1[lane * 2], f1b = pr1[lane * 2 + 1];
    const float4 f2a = pr2[lane * 2], f2b = pr2[lane * 2 + 1];
    const float4 f3a = pr3[lane * 2], f3b = pr3[lane * 2 + 1];

    // ---- stage target rows: wave w packs staged rows w and w+8 (ri < 14).
    #pragma unroll
    for (int i = 0; i < 2; ++i) {
        const int ri = wave + 8 * i;
        if (ri < SROWS) {
            const int gyt = y0 - 3 + ri;
            uint32_t wv = 0u, h1 = 0u, h2 = 0u, h3 = 0u;
            if ((unsigned)gyt < (unsigned)HH) {        // wave-uniform branch
                const int4* trow = (const int4*)(tgt_b + gyt * WW);
                const int4 t0 = trow[lane * 2];
                const int4 t1 = trow[lane * 2 + 1];
                wv = (1u << t0.x)        | (1u << (t0.y + 4))
                   | (1u << (t0.z + 8))  | (1u << (t0.w + 12))
                   | (1u << (t1.x + 16)) | (1u << (t1.y + 20))
                   | (1u << (t1.z + 24)) | (1u << (t1.w + 28));
                uint32_t wl = __shfl_up(wv, 1, 64);   if (lane == 0)  wl = 0u;
                uint32_t wr = __shfl_down(wv, 1, 64); if (lane == 63) wr = 0u;
                h1 = wv | ((wv << 4)  | (wl >> 28)) | ((wv >> 4)  | (wr << 28));
                h2 = h1 | ((wv << 8)  | (wl >> 24)) | ((wv >> 8)  | (wr << 24));
                h3 = h2 | ((wv << 12) | (wl >> 20)) | ((wv >> 12) | (wr << 20));
            }
            hrow[ri * 64 + lane] = make_uint4(h1, h2, h3, wv);
        }
    }
    __syncthreads();

    // ---- vertical OR for this wave's row: 7 x ds_read_b128.
    const int lr = wave + 3;
    const uint4 r0 = hrow[(lr - 3) * 64 + lane];
    const uint4 r1 = hrow[(lr - 2) * 64 + lane];
    const uint4 r2 = hrow[(lr - 1) * 64 + lane];
    const uint4 r3 = hrow[(lr    ) * 64 + lane];
    const uint4 r4 = hrow[(lr + 1) * 64 + lane];
    const uint4 r5 = hrow[(lr + 2) * 64 + lane];
    const uint4 r6 = hrow[(lr + 3) * 64 + lane];
    const uint32_t p1 = r2.x | r3.x | r4.x;
    const uint32_t p2 = r1.y | r2.y | r3.y | r4.y | r5.y;
    const uint32_t p3 = r0.z | r1.z | r2.z | r3.z | r4.z | r5.z | r6.z;
    const uint32_t cw = r3.w;

    const float pv[3][8] = {
        {f1a.x, f1a.y, f1a.z, f1a.w, f1b.x, f1b.y, f1b.z, f1b.w},
        {f2a.x, f2a.y, f2a.z, f2a.w, f2b.x, f2b.y, f2b.z, f2b.w},
        {f3a.x, f3a.y, f3a.z, f3a.w, f3b.x, f3b.y, f3b.z, f3b.w}};

    float num[3] = {0.f, 0.f, 0.f};
    int   den[3] = {0, 0, 0};
    int   mc [3] = {0, 0, 0};

    #pragma unroll
    for (int j = 0; j < 8; ++j) {
        const uint32_t q1 = (p1 >> (4 * j)) & 15u;
        const uint32_t q2 = (p2 >> (4 * j)) & 15u;
        const uint32_t q3 = (p3 >> (4 * j)) & 15u;
        const uint32_t cb = (cw >> (4 * j)) & 15u;
        #pragma unroll
        for (int k = 0; k < 3; ++k) {
            const uint32_t cm = 2u << k;              // 1<<(k+1)
            const bool v = (cb & cm) != 0u;
            const uint32_t sel = v ? (15u & ~cm) : cm;
            const uint32_t a1 = q1 & sel;
            const uint32_t a2 = q2 & sel;
            const uint32_t a3 = q3 & sel;
            const float df  = a1 ? 1.f : (a2 ? 2.f : 3.f);
            const float err = fabsf(pv[k][j] - (v ? 1.f : 0.f));
            num[k] += a3 ? err * df : 0.f;
            den[k] += a3 ? 1 : 0;
            mc [k] += v  ? 1 : 0;
        }
    }

    // ---- block reduction (per-lane den/mc <= 8 -> 16-bit packing safe).
    int pk0 = den[0] | (den[1] << 16);
    int pk1 = den[2] | (mc[0] << 16);
    int pk2 = mc[1]  | (mc[2] << 16);
    #pragma unroll
    for (int off = 32; off; off >>= 1) {
        num[0] += __shfl_down(num[0], off, 64);
        num[1] += __shfl_down(num[1], off, 64);
        num[2] += __shfl_down(num[2], off, 64);
        pk0    += __shfl_down(pk0,    off, 64);
        pk1    += __shfl_down(pk1,    off, 64);
        pk2    += __shfl_down(pk2,    off, 64);
    }
    if (lane == 0) {
        redf[wave][0] = num[0]; redf[wave][1] = num[1]; redf[wave][2] = num[2];
        redi[wave][0] = pk0;    redi[wave][1] = pk1;    redi[wave][2] = pk2;
    }
    __syncthreads();
    if (tid == 0) {
        const int blockFlat = b * 64 + strip;
        float n0 = 0.f, n1 = 0.f, n2 = 0.f;
        int s0 = 0, s1 = 0, s2 = 0;
        #pragma unroll
        for (int w = 0; w < 8; ++w) {
            n0 += redf[w][0]; n1 += redf[w][1]; n2 += redf[w][2];
            s0 += redi[w][0]; s1 += redi[w][1]; s2 += redi[w][2];
        }
        float* wp = ws + PART_OFF;
        wp[0 * NBLK + blockFlat] = n0;
        wp[1 * NBLK + blockFlat] = n1;
        wp[2 * NBLK + blockFlat] = n2;
        wp[3 * NBLK + blockFlat] = (float)(s0 & 0xFFFF);
        wp[4 * NBLK + blockFlat] = (float)(s0 >> 16);
        wp[5 * NBLK + blockFlat] = (float)(s1 & 0xFFFF);
        wp[6 * NBLK + blockFlat] = (float)(s1 >> 16);
        wp[7 * NBLK + blockFlat] = (float)(s2 & 0xFFFF);
        wp[8 * NBLK + blockFlat] = (float)(s2 >> 16);
        __threadfence();                         // partials visible device-wide
        const int old = atomicAdd((int*)ws, 1);  // counter zeroed by memset
        isLast = (old == NBLK - 1) ? 1 : 0;
    }
    __syncthreads();
    if (!isLast) return;

    // ==== last block: reduce 72 groups x 64 strip-partials, emit scalar.
    __threadfence();                             // acquire partials
    const float* wp = ws + PART_OFF;

    // wave w handles groups G = w*9 .. w*9+8;  G = s*8 + b2.
    float sv[9];
    #pragma unroll
    for (int i = 0; i < 9; ++i) {
        const int G = wave * 9 + i;
        const int s = G >> 3, b2 = G & 7;
        sv[i] = wp[s * NBLK + b2 * 64 + lane];
    }
    #pragma unroll
    for (int i = 0; i < 9; ++i) {
        #pragma unroll
        for (int off = 32; off; off >>= 1) sv[i] += __shfl_down(sv[i], off, 64);
    }
    if (lane == 0) {
        #pragma unroll
        for (int i = 0; i < 9; ++i) ws2[wave * 9 + i] = sv[i];
    }
    __syncthreads();

    if (wave == 0) {
        float loss = 0.f, incl = 0.f;
        if (lane < 24) {
            const int b2 = lane / 3, cc = lane - b2 * 3;
            const float numv = ws2[(0 + cc) * 8 + b2];        // s = cc
            const float denv = ws2[(3 + cc) * 8 + b2];        // s = 3+cc
            const float mcv  = ws2[(6 + cc) * 8 + b2];        // s = 6+cc
            const bool trivial = (mcv == 0.f) || (mcv == (float)(HH * WW));
            if (trivial) {
                incl = 1.f; loss = 0.f;        // band = whole image, num = 0
            } else if (denv >= 32.f) {
                incl = 1.f;
                loss = numv / (denv + 1e-6f);
            }
        }
        #pragma unroll
        for (int off = 32; off; off >>= 1) {
            loss += __shfl_down(loss, off, 64);
            incl += __shfl_down(incl, off, 64);
        }
        if (lane == 0) out[0] = loss / (incl + 1e-6f);
    }
}

extern "C" void kernel_launch(void* const* d_in, const int* in_sizes, int n_in,
                              void* d_out, int out_size, void* d_ws, size_t ws_size,
                              hipStream_t stream)
{
    const float* probs  = (const float*)d_in[0];
    const int*   target = (const int*)d_in[1];
    float* out = (float*)d_out;
    float* ws  = (float*)d_ws;

    hipMemsetAsync(ws, 0, 4, stream);      // zero the completion counter
    dim3 grid(64, BB);                     // 64 row-strips x 8 images
    gsl_fused<<<grid, 512, 0, stream>>>(probs, target, ws, out);
}

// Round 6
// 88.109 us; speedup vs baseline: 1.0778x; 1.0778x over previous
//
#include <hip/hip_runtime.h>

// GeneralizedSurfaceLoss on MI355X.
// Chamfer == Chebyshev distance; BAND_WIDTH=3 => 7x7 neighborhood test.
// R1: killed global-atomic serialization (483 -> 95 us).
// R2: nibble-packed separable window (8 px per uint32, shfl horizontal OR,
//     ds_read_b128 vertical OR), strip blocks + finish kernel (84.5 us).
// R4: 512-thr blocks, hoisted probs loads (neutral).
// R5: fused w/ memset node + threadfence last-block (95.0 -> regression).
// R6: TRUE single node. No memset: counter base is the documented 0xAA ws
//     poison (0xAAAAAAAA), fallback base 0. No threadfence: partials stored
//     as relaxed agent-scope atomics; counter is acq_rel agent-scope RMW.

#define HH 512
#define WW 512
#define BB 8
#define STRIP 8               // output rows per block; one row per wave
#define SROWS (STRIP + 6)     // staged rows incl. halo = 14
#define NBLK 512              // 64 strips * 8 images
#define PART_OFF 64           // float offset of partials (counter at [0])

// ws floats: [0] = completion counter (starts at 0xAAAAAAAA poison each call)
//            [PART_OFF + s*NBLK + blockFlat], s: 0..2=num,3..5=den,6..8=mc,
//            blockFlat = b*64 + strip.

__global__ __launch_bounds__(512) void gsl_fused(
    const float* __restrict__ probs,   // [B,4,H,W]
    const int*   __restrict__ target,  // [B,H,W]
    float* __restrict__ ws,
    float* __restrict__ out)
{
    __shared__ uint4 hrow[SROWS * 64];   // {h1,h2,h3,center} per (row,lane)
    __shared__ float redf[8][3];
    __shared__ int   redi[8][3];
    __shared__ int   isLast;
    __shared__ float ws2[72];

    const int tid   = threadIdx.x;
    const int lane  = tid & 63;
    const int wave  = tid >> 6;          // 0..7 = output row within strip
    const int strip = blockIdx.x;        // 0..63
    const int b     = blockIdx.y;        // 0..7
    const int y0    = strip * STRIP;
    const int gy    = y0 + wave;
    const int* __restrict__ tgt_b = target + b * (HH * WW);

    // ---- probs for this wave's row: 6 independent float4 loads up front.
    const float4* pr1 = (const float4*)(probs + (size_t)(((b * 4) + 1) * HH + gy) * WW);
    const float4* pr2 = (const float4*)(probs + (size_t)(((b * 4) + 2) * HH + gy) * WW);
    const float4* pr3 = (const float4*)(probs + (size_t)(((b * 4) + 3) * HH + gy) * WW);
    const float4 f1a = pr1[lane * 2], f1b = pr1[lane * 2 + 1];
    const float4 f2a = pr2[lane * 2], f2b = pr2[lane * 2 + 1];
    const float4 f3a = pr3[lane * 2], f3b = pr3[lane * 2 + 1];

    // ---- stage target rows: wave w packs staged rows w and w+8 (ri < 14).
    #pragma unroll
    for (int i = 0; i < 2; ++i) {
        const int ri = wave + 8 * i;
        if (ri < SROWS) {
            const int gyt = y0 - 3 + ri;
            uint32_t wv = 0u, h1 = 0u, h2 = 0u, h3 = 0u;
            if ((unsigned)gyt < (unsigned)HH) {        // wave-uniform branch
                const int4* trow = (const int4*)(tgt_b + gyt * WW);
                const int4 t0 = trow[lane * 2];
                const int4 t1 = trow[lane * 2 + 1];
                wv = (1u << t0.x)        | (1u << (t0.y + 4))
                   | (1u << (t0.z + 8))  | (1u << (t0.w + 12))
                   | (1u << (t1.x + 16)) | (1u << (t1.y + 20))
                   | (1u << (t1.z + 24)) | (1u << (t1.w + 28));
                uint32_t wl = __shfl_up(wv, 1, 64);   if (lane == 0)  wl = 0u;
                uint32_t wr = __shfl_down(wv, 1, 64); if (lane == 63) wr = 0u;
                h1 = wv | ((wv << 4)  | (wl >> 28)) | ((wv >> 4)  | (wr << 28));
                h2 = h1 | ((wv << 8)  | (wl >> 24)) | ((wv >> 8)  | (wr << 24));
                h3 = h2 | ((wv << 12) | (wl >> 20)) | ((wv >> 12) | (wr << 20));
            }
            hrow[ri * 64 + lane] = make_uint4(h1, h2, h3, wv);
        }
    }
    __syncthreads();

    // ---- vertical OR for this wave's row: 7 x ds_read_b128.
    const int lr = wave + 3;
    const uint4 r0 = hrow[(lr - 3) * 64 + lane];
    const uint4 r1 = hrow[(lr - 2) * 64 + lane];
    const uint4 r2 = hrow[(lr - 1) * 64 + lane];
    const uint4 r3 = hrow[(lr    ) * 64 + lane];
    const uint4 r4 = hrow[(lr + 1) * 64 + lane];
    const uint4 r5 = hrow[(lr + 2) * 64 + lane];
    const uint4 r6 = hrow[(lr + 3) * 64 + lane];
    const uint32_t p1 = r2.x | r3.x | r4.x;
    const uint32_t p2 = r1.y | r2.y | r3.y | r4.y | r5.y;
    const uint32_t p3 = r0.z | r1.z | r2.z | r3.z | r4.z | r5.z | r6.z;
    const uint32_t cw = r3.w;

    const float pv[3][8] = {
        {f1a.x, f1a.y, f1a.z, f1a.w, f1b.x, f1b.y, f1b.z, f1b.w},
        {f2a.x, f2a.y, f2a.z, f2a.w, f2b.x, f2b.y, f2b.z, f2b.w},
        {f3a.x, f3a.y, f3a.z, f3a.w, f3b.x, f3b.y, f3b.z, f3b.w}};

    float num[3] = {0.f, 0.f, 0.f};
    int   den[3] = {0, 0, 0};
    int   mc [3] = {0, 0, 0};

    #pragma unroll
    for (int j = 0; j < 8; ++j) {
        const uint32_t q1 = (p1 >> (4 * j)) & 15u;
        const uint32_t q2 = (p2 >> (4 * j)) & 15u;
        const uint32_t q3 = (p3 >> (4 * j)) & 15u;
        const uint32_t cb = (cw >> (4 * j)) & 15u;
        #pragma unroll
        for (int k = 0; k < 3; ++k) {
            const uint32_t cm = 2u << k;              // 1<<(k+1)
            const bool v = (cb & cm) != 0u;
            const uint32_t sel = v ? (15u & ~cm) : cm;
            const uint32_t a1 = q1 & sel;
            const uint32_t a2 = q2 & sel;
            const uint32_t a3 = q3 & sel;
            const float df  = a1 ? 1.f : (a2 ? 2.f : 3.f);
            const float err = fabsf(pv[k][j] - (v ? 1.f : 0.f));
            num[k] += a3 ? err * df : 0.f;
            den[k] += a3 ? 1 : 0;
            mc [k] += v  ? 1 : 0;
        }
    }

    // ---- block reduction (per-lane den/mc <= 8 -> 16-bit packing safe).
    int pk0 = den[0] | (den[1] << 16);
    int pk1 = den[2] | (mc[0] << 16);
    int pk2 = mc[1]  | (mc[2] << 16);
    #pragma unroll
    for (int off = 32; off; off >>= 1) {
        num[0] += __shfl_down(num[0], off, 64);
        num[1] += __shfl_down(num[1], off, 64);
        num[2] += __shfl_down(num[2], off, 64);
        pk0    += __shfl_down(pk0,    off, 64);
        pk1    += __shfl_down(pk1,    off, 64);
        pk2    += __shfl_down(pk2,    off, 64);
    }
    if (lane == 0) {
        redf[wave][0] = num[0]; redf[wave][1] = num[1]; redf[wave][2] = num[2];
        redi[wave][0] = pk0;    redi[wave][1] = pk1;    redi[wave][2] = pk2;
    }
    __syncthreads();
    if (tid == 0) {
        const int blockFlat = b * 64 + strip;
        float n0 = 0.f, n1 = 0.f, n2 = 0.f;
        int s0 = 0, s1 = 0, s2 = 0;
        #pragma unroll
        for (int w = 0; w < 8; ++w) {
            n0 += redf[w][0]; n1 += redf[w][1]; n2 += redf[w][2];
            s0 += redi[w][0]; s1 += redi[w][1]; s2 += redi[w][2];
        }
        float* wp = ws + PART_OFF;
        const float vals[9] = {
            n0, n1, n2,
            (float)(s0 & 0xFFFF), (float)(s0 >> 16), (float)(s1 & 0xFFFF),
            (float)(s1 >> 16),    (float)(s2 & 0xFFFF), (float)(s2 >> 16)};
        #pragma unroll
        for (int s = 0; s < 9; ++s)
            __hip_atomic_store(&wp[s * NBLK + blockFlat], vals[s],
                               __ATOMIC_RELAXED, __HIP_MEMORY_SCOPE_AGENT);
        // release RMW: orders the agent-scope stores, no L2 writeback needed
        const unsigned old = __hip_atomic_fetch_add((unsigned*)ws, 1u,
                               __ATOMIC_ACQ_REL, __HIP_MEMORY_SCOPE_AGENT);
        // ws is re-poisoned to 0xAA bytes before every launch -> base
        // 0xAAAAAAAA; fallback base 0 in case a path zero-initializes.
        isLast = (old == 0xAAAAAAAAu + (NBLK - 1u)) || (old == NBLK - 1u);
    }
    __syncthreads();
    if (!isLast) return;

    // ==== last block: reduce 72 groups x 64 strip-partials, emit scalar.
    const float* wp = ws + PART_OFF;

    // wave w handles groups G = w*9 .. w*9+8;  G = s*8 + b2.
    float sv[9];
    #pragma unroll
    for (int i = 0; i < 9; ++i) {
        const int G = wave * 9 + i;
        const int s = G >> 3, b2 = G & 7;
        sv[i] = __hip_atomic_load(&wp[s * NBLK + b2 * 64 + lane],
                                  __ATOMIC_RELAXED, __HIP_MEMORY_SCOPE_AGENT);
    }
    #pragma unroll
    for (int i = 0; i < 9; ++i) {
        #pragma unroll
        for (int off = 32; off; off >>= 1) sv[i] += __shfl_down(sv[i], off, 64);
    }
    if (lane == 0) {
        #pragma unroll
        for (int i = 0; i < 9; ++i) ws2[wave * 9 + i] = sv[i];
    }
    __syncthreads();

    if (wave == 0) {
        float loss = 0.f, incl = 0.f;
        if (lane < 24) {
            const int b2 = lane / 3, cc = lane - b2 * 3;
            const float numv = ws2[(0 + cc) * 8 + b2];        // s = cc
            const float denv = ws2[(3 + cc) * 8 + b2];        // s = 3+cc
            const float mcv  = ws2[(6 + cc) * 8 + b2];        // s = 6+cc
            const bool trivial = (mcv == 0.f) || (mcv == (float)(HH * WW));
            if (trivial) {
                incl = 1.f; loss = 0.f;        // band = whole image, num = 0
            } else if (denv >= 32.f) {
                incl = 1.f;
                loss = numv / (denv + 1e-6f);
            }
        }
        #pragma unroll
        for (int off = 32; off; off >>= 1) {
            loss += __shfl_down(loss, off, 64);
            incl += __shfl_down(incl, off, 64);
        }
        if (lane == 0) out[0] = loss / (incl + 1e-6f);
    }
}

extern "C" void kernel_launch(void* const* d_in, const int* in_sizes, int n_in,
                              void* d_out, int out_size, void* d_ws, size_t ws_size,
                              hipStream_t stream)
{
    const float* probs  = (const float*)d_in[0];
    const int*   target = (const int*)d_in[1];
    float* out = (float*)d_out;
    float* ws  = (float*)d_ws;

    dim3 grid(64, BB);                     // 64 row-strips x 8 images
    gsl_fused<<<grid, 512, 0, stream>>>(probs, target, ws, out);
}

// Round 7
// 85.108 us; speedup vs baseline: 1.1158x; 1.0353x over previous
//
#include <hip/hip_runtime.h>

// GeneralizedSurfaceLoss on MI355X.
// Chamfer == Chebyshev distance; BAND_WIDTH=3 => 7x7 neighborhood test.
// R1: killed global-atomic serialization (483 -> 95 us).
// R2: nibble-packed separable window (8 px per uint32, shfl horizontal OR,
//     ds_read_b128 vertical OR), strip blocks + finish kernel -> 84.5 us BEST.
// R4-R6: fused/single-node variants all slower (85.6 / 95.0 / 88.1):
//     last-block counter serialization + drained-machine tail >= a second
//     kernel node; threadfence (buffer_wbl2 x512) and memset node cost ~7 us.
// R7: revert to the measured-best R2 structure. Stage1 HBM traffic is the
//     information-theoretic minimum (probs[1:] 25MB + target 8MB, each byte
//     read once, coalesced); remaining window = harness fill/restore/launch.

#define HH 512
#define WW 512
#define BB 8
#define STRIP 8               // output rows per block
#define SROWS (STRIP + 6)     // staged rows incl. halo = 14
#define NBLK 512              // 64 strips * 8 images

// ws: 9 arrays of NBLK floats; slot s = grp*3+cc (grp: 0=num,1=den,2=mc),
// element index blockFlat = b*64 + strip.

__global__ __launch_bounds__(256) void gsl_stage1(
    const float* __restrict__ probs,   // [B,4,H,W]
    const int*   __restrict__ target,  // [B,H,W]
    float* __restrict__ ws)
{
    __shared__ uint4 hrow[SROWS * 64];   // {h1,h2,h3,center} per (row,lane)
    __shared__ float redf[4][3];
    __shared__ int   redi[4][3];

    const int tid   = threadIdx.x;
    const int lane  = tid & 63;
    const int wave  = tid >> 6;
    const int strip = blockIdx.x;        // 0..63
    const int b     = blockIdx.y;        // 0..7
    const int y0    = strip * STRIP;
    const int* __restrict__ tgt_b = target + b * (HH * WW);

    // ---- phase 1: pack rows y0-3 .. y0+STRIP+2 (wave-cyclic row assignment)
    #pragma unroll
    for (int i = 0; i < 4; ++i) {
        const int ri = wave + 4 * i;
        if (ri < SROWS) {
            const int gy = y0 - 3 + ri;
            uint32_t wv = 0u, h1 = 0u, h2 = 0u, h3 = 0u;
            if ((unsigned)gy < (unsigned)HH) {
                const int4* trow = (const int4*)(tgt_b + gy * WW);
                const int4 t0 = trow[lane * 2];
                const int4 t1 = trow[lane * 2 + 1];
                wv = (1u << t0.x)        | (1u << (t0.y + 4))
                   | (1u << (t0.z + 8))  | (1u << (t0.w + 12))
                   | (1u << (t1.x + 16)) | (1u << (t1.y + 20))
                   | (1u << (t1.z + 24)) | (1u << (t1.w + 28));
                uint32_t wl = __shfl_up(wv, 1, 64);   if (lane == 0)  wl = 0u;
                uint32_t wr = __shfl_down(wv, 1, 64); if (lane == 63) wr = 0u;
                h1 = wv | ((wv << 4)  | (wl >> 28)) | ((wv >> 4)  | (wr << 28));
                h2 = h1 | ((wv << 8)  | (wl >> 24)) | ((wv >> 8)  | (wr << 24));
                h3 = h2 | ((wv << 12) | (wl >> 20)) | ((wv >> 12) | (wr << 20));
            }
            hrow[ri * 64 + lane] = make_uint4(h1, h2, h3, wv);
        }
    }
    __syncthreads();

    // ---- phase 2: each wave computes 2 output rows
    float num[3] = {0.f, 0.f, 0.f};
    int   den[3] = {0, 0, 0};
    int   mc [3] = {0, 0, 0};

    #pragma unroll
    for (int t = 0; t < 2; ++t) {
        const int yo = wave * 2 + t;
        const int gy = y0 + yo;
        const int lr = yo + 3;

        const float4* pr1 = (const float4*)(probs + (size_t)(((b * 4) + 1) * HH + gy) * WW);
        const float4* pr2 = (const float4*)(probs + (size_t)(((b * 4) + 2) * HH + gy) * WW);
        const float4* pr3 = (const float4*)(probs + (size_t)(((b * 4) + 3) * HH + gy) * WW);
        const float4 f1a = pr1[lane * 2], f1b = pr1[lane * 2 + 1];
        const float4 f2a = pr2[lane * 2], f2b = pr2[lane * 2 + 1];
        const float4 f3a = pr3[lane * 2], f3b = pr3[lane * 2 + 1];

        const uint4 r0 = hrow[(lr - 3) * 64 + lane];
        const uint4 r1 = hrow[(lr - 2) * 64 + lane];
        const uint4 r2 = hrow[(lr - 1) * 64 + lane];
        const uint4 r3 = hrow[(lr    ) * 64 + lane];
        const uint4 r4 = hrow[(lr + 1) * 64 + lane];
        const uint4 r5 = hrow[(lr + 2) * 64 + lane];
        const uint4 r6 = hrow[(lr + 3) * 64 + lane];
        const uint32_t p1 = r2.x | r3.x | r4.x;
        const uint32_t p2 = r1.y | r2.y | r3.y | r4.y | r5.y;
        const uint32_t p3 = r0.z | r1.z | r2.z | r3.z | r4.z | r5.z | r6.z;
        const uint32_t cw = r3.w;

        const float pv[3][8] = {
            {f1a.x, f1a.y, f1a.z, f1a.w, f1b.x, f1b.y, f1b.z, f1b.w},
            {f2a.x, f2a.y, f2a.z, f2a.w, f2b.x, f2b.y, f2b.z, f2b.w},
            {f3a.x, f3a.y, f3a.z, f3a.w, f3b.x, f3b.y, f3b.z, f3b.w}};

        #pragma unroll
        for (int j = 0; j < 8; ++j) {
            const uint32_t q1 = (p1 >> (4 * j)) & 15u;
            const uint32_t q2 = (p2 >> (4 * j)) & 15u;
            const uint32_t q3 = (p3 >> (4 * j)) & 15u;
            const uint32_t cb = (cw >> (4 * j)) & 15u;
            #pragma unroll
            for (int k = 0; k < 3; ++k) {
                const uint32_t cm = 2u << k;          // 1<<(k+1)
                const bool v = (cb & cm) != 0u;
                const uint32_t sel = v ? (15u & ~cm) : cm;
                const uint32_t a1 = q1 & sel;
                const uint32_t a2 = q2 & sel;
                const uint32_t a3 = q3 & sel;
                const float df  = a1 ? 1.f : (a2 ? 2.f : 3.f);
                const float err = fabsf(pv[k][j] - (v ? 1.f : 0.f));
                num[k] += a3 ? err * df : 0.f;
                den[k] += a3 ? 1 : 0;
                mc [k] += v  ? 1 : 0;
            }
        }
    }

    // ---- block reduction (den/mc <= 1024 after 64-lane sum: 16-bit safe)
    int pk0 = den[0] | (den[1] << 16);
    int pk1 = den[2] | (mc[0] << 16);
    int pk2 = mc[1]  | (mc[2] << 16);
    #pragma unroll
    for (int off = 32; off; off >>= 1) {
        num[0] += __shfl_down(num[0], off, 64);
        num[1] += __shfl_down(num[1], off, 64);
        num[2] += __shfl_down(num[2], off, 64);
        pk0    += __shfl_down(pk0,    off, 64);
        pk1    += __shfl_down(pk1,    off, 64);
        pk2    += __shfl_down(pk2,    off, 64);
    }
    if (lane == 0) {
        redf[wave][0] = num[0]; redf[wave][1] = num[1]; redf[wave][2] = num[2];
        redi[wave][0] = pk0;    redi[wave][1] = pk1;    redi[wave][2] = pk2;
    }
    __syncthreads();
    if (tid == 0) {
        const int blockFlat = b * 64 + strip;
        float n0 = 0.f, n1 = 0.f, n2 = 0.f;
        int s0 = 0, s1 = 0, s2 = 0;
        #pragma unroll
        for (int w = 0; w < 4; ++w) {
            n0 += redf[w][0]; n1 += redf[w][1]; n2 += redf[w][2];
            s0 += redi[w][0]; s1 += redi[w][1]; s2 += redi[w][2];
        }
        ws[(0 * 3 + 0) * NBLK + blockFlat] = n0;
        ws[(0 * 3 + 1) * NBLK + blockFlat] = n1;
        ws[(0 * 3 + 2) * NBLK + blockFlat] = n2;
        ws[(1 * 3 + 0) * NBLK + blockFlat] = (float)(s0 & 0xFFFF);
        ws[(1 * 3 + 1) * NBLK + blockFlat] = (float)(s0 >> 16);
        ws[(1 * 3 + 2) * NBLK + blockFlat] = (float)(s1 & 0xFFFF);
        ws[(2 * 3 + 0) * NBLK + blockFlat] = (float)(s1 >> 16);
        ws[(2 * 3 + 1) * NBLK + blockFlat] = (float)(s2 & 0xFFFF);
        ws[(2 * 3 + 2) * NBLK + blockFlat] = (float)(s2 >> 16);
    }
}

// Single block, 16 waves: 72 group-reductions of 64 strip-partials, then the
// final 24-mask loss in wave 0.
__global__ __launch_bounds__(1024) void gsl_finish(
    const float* __restrict__ ws, float* __restrict__ out)
{
    __shared__ float ws2[72];
    const int tid = threadIdx.x, lane = tid & 63, wave = tid >> 6;

    for (int g = wave; g < 72; g += 16) {
        const int grp = g / 24, rem = g - grp * 24;
        const int bb = rem / 3, cc = rem - bb * 3;
        float s = ws[(grp * 3 + cc) * NBLK + bb * 64 + lane];
        #pragma unroll
        for (int off = 32; off; off >>= 1) s += __shfl_down(s, off, 64);
        if (lane == 0) ws2[g] = s;
    }
    __syncthreads();

    if (wave == 0) {
        float loss = 0.f, incl = 0.f;
        if (lane < 24) {
            const float num = ws2[lane];
            const float den = ws2[24 + lane];
            const float mcv = ws2[48 + lane];
            const bool trivial = (mcv == 0.f) || (mcv == (float)(HH * WW));
            if (trivial) {
                incl = 1.f; loss = 0.f;        // band = whole image, num = 0
            } else if (den >= 32.f) {
                incl = 1.f;
                loss = num / (den + 1e-6f);
            }
        }
        #pragma unroll
        for (int off = 32; off; off >>= 1) {
            loss += __shfl_down(loss, off, 64);
            incl += __shfl_down(incl, off, 64);
        }
        if (lane == 0) out[0] = loss / (incl + 1e-6f);
    }
}

extern "C" void kernel_launch(void* const* d_in, const int* in_sizes, int n_in,
                              void* d_out, int out_size, void* d_ws, size_t ws_size,
                              hipStream_t stream)
{
    const float* probs  = (const float*)d_in[0];
    const int*   target = (const int*)d_in[1];
    float* out = (float*)d_out;
    float* ws  = (float*)d_ws;

    dim3 grid1(64, BB);        // 64 row-strips x 8 images
    gsl_stage1<<<grid1, 256, 0, stream>>>(probs, target, ws);
    gsl_finish<<<1, 1024, 0, stream>>>(ws, out);
}